// Round 3
// baseline (1126.496 us; speedup 1.0000x reference)
//
#include <hip/hip_runtime.h>
#include <math.h>

#define NNODES 8192
#define DDIM   64
#define NLAYER 9
#define NMLP   3

// ---------------- weight transpose prep (once per launch) ----------------
// WtA[l][k][c] : c<64 -> conv_W[l][c][k] ; c>=64 -> gru_Whh[l][c-64][k]   (9*64*256)
// WtI[l][k][c] : gru_Wih[l][c][k]                                         (9*64*192)
// WtM[m][k][c] : mlp_W[m][c][k]                                           (3*64*64)
__global__ void prep_weights(const float* __restrict__ conv_W,
                             const float* __restrict__ gru_Whh,
                             const float* __restrict__ gru_Wih,
                             const float* __restrict__ mlp_W,
                             float* __restrict__ WtA,
                             float* __restrict__ WtI,
                             float* __restrict__ WtM)
{
    int tid = blockIdx.x * blockDim.x + threadIdx.x;
    const int nA = NLAYER * 64 * 256;   // 147456
    const int nI = NLAYER * 64 * 192;   // 110592
    const int nM = NMLP * 64 * 64;      // 12288
    if (tid < nA) {
        int l = tid / 16384, rem = tid % 16384;
        int k = rem / 256, c = rem % 256;
        float v = (c < 64) ? conv_W[l * 4096 + c * 64 + k]
                           : gru_Whh[l * 12288 + (c - 64) * 64 + k];
        WtA[tid] = v;
    } else if (tid < nA + nI) {
        int t = tid - nA;
        int l = t / 12288, rem = t % 12288;
        int k = rem / 192, c = rem % 192;
        WtI[t] = gru_Wih[l * 12288 + c * 64 + k];
    } else if (tid < nA + nI + nM) {
        int t = tid - nA - nI;
        int m = t / 4096, rem = t % 4096;
        int k = rem / 64, c = rem % 64;
        WtM[t] = mlp_W[m * 4096 + c * 64 + k];
    }
}

// ---------------- h0 init + degree-count zero ----------------
__global__ void init_h(const float* __restrict__ node_feat,
                       float* __restrict__ h, int* __restrict__ counts)
{
    int tid = blockIdx.x * blockDim.x + threadIdx.x;
    if (tid < NNODES * DDIM) {
        int n = tid >> 6, d = tid & 63;
        h[tid] = (d == 0) ? node_feat[n] : 0.f;
    }
    if (tid < NNODES) counts[tid] = 0;
}

// ---------------- CSC build (by dst) ----------------
__global__ void count_deg(const int* __restrict__ dst, int E, int* __restrict__ counts)
{
    int tid = blockIdx.x * blockDim.x + threadIdx.x;
    if (tid < E) atomicAdd(&counts[dst[tid]], 1);
}

__global__ void scan_deg(const int* __restrict__ counts,
                         int* __restrict__ row_ptr, int* __restrict__ row_fill)
{
    __shared__ int partial[256];
    int t = threadIdx.x;
    int local[32];
    int base = t * 32;
    int s = 0;
    #pragma unroll
    for (int i = 0; i < 32; i++) { local[i] = counts[base + i]; s += local[i]; }
    partial[t] = s;
    __syncthreads();
    for (int off = 1; off < 256; off <<= 1) {
        int v = (t >= off) ? partial[t - off] : 0;
        __syncthreads();
        partial[t] += v;
        __syncthreads();
    }
    int run = (t == 0) ? 0 : partial[t - 1];
    #pragma unroll
    for (int i = 0; i < 32; i++) {
        row_ptr[base + i] = run;
        row_fill[base + i] = run;
        run += local[i];
    }
    if (t == 255) row_ptr[NNODES] = run;
}

__global__ void scatter_edges(const int* __restrict__ src, const int* __restrict__ dst, int E,
                              int* __restrict__ row_fill, int* __restrict__ col_idx)
{
    int tid = blockIdx.x * blockDim.x + threadIdx.x;
    if (tid < E) {
        int pos = atomicAdd(&row_fill[dst[tid]], 1);
        col_idx[pos] = src[tid];
    }
}

// ---------------- per-layer: hl = h@W^T+b ; gh = h@Whh^T+bhh (fused, width 256) ----
__global__ __launch_bounds__(256)
void layer_pre(const float* __restrict__ h,
               const float* __restrict__ Wt,   // [64][256] for this layer
               const float* __restrict__ bA,   // conv_b   [64]
               const float* __restrict__ bH,   // gru_bhh  [192]
               float* __restrict__ hl, float* __restrict__ gh)
{
    __shared__ float ht[16][64];
    int c = threadIdx.x;
    int row0 = blockIdx.x * 16;
    ((float4*)ht)[c] = ((const float4*)(h + row0 * 64))[c];
    __syncthreads();
    float bias = (c < 64) ? bA[c] : bH[c - 64];
    float acc[16];
    #pragma unroll
    for (int j = 0; j < 16; j++) acc[j] = bias;
    #pragma unroll 8
    for (int k = 0; k < 64; k++) {
        float w = Wt[k * 256 + c];
        #pragma unroll
        for (int j = 0; j < 16; j++) acc[j] = fmaf(ht[j][k], w, acc[j]);
    }
    if (c < 64) {
        #pragma unroll
        for (int j = 0; j < 16; j++) hl[(row0 + j) * 64 + c] = acc[j];
    } else {
        int cc = c - 64;
        #pragma unroll
        for (int j = 0; j < 16; j++) gh[(row0 + j) * 192 + cc] = acc[j];
    }
}

// ---------------- aggregation: a[n] = hl[n] + sum_{e:dst=n} hl[src_e] ----------------
__global__ __launch_bounds__(256)
void aggregate(const float* __restrict__ hl,
               const int* __restrict__ row_ptr,
               const int* __restrict__ col_idx,
               float* __restrict__ a)
{
    int wave = threadIdx.x >> 6, lane = threadIdx.x & 63;
    int node = blockIdx.x * 4 + wave;
    int s0 = row_ptr[node], s1 = row_ptr[node + 1];
    float acc = hl[node * 64 + lane];           // self loop
    for (int e = s0; e < s1; ++e) {
        int sn = col_idx[e];
        acc += hl[sn * 64 + lane];
    }
    a[node * 64 + lane] = acc;
}

// ---------------- GRU gates: gi = a@Wih^T+bih ; combine with gh, h ----------------
__device__ __forceinline__ float sigmoidf_(float x) { return 1.f / (1.f + __expf(-x)); }
__device__ __forceinline__ float tanhf_(float x) {
    float e = __expf(-2.f * fabsf(x));
    float t = (1.f - e) / (1.f + e);
    return copysignf(t, x);
}

__global__ __launch_bounds__(256)
void layer_gru(const float* __restrict__ a,
               const float* __restrict__ WtI_l,  // [64][192]
               const float* __restrict__ bih,    // [192]
               const float* __restrict__ gh,
               float* __restrict__ h)
{
    __shared__ float at[16][64];
    int tid = threadIdx.x;
    int d = tid & 63, rg = tid >> 6;
    int row0 = blockIdx.x * 16;
    ((float4*)at)[tid] = ((const float4*)(a + row0 * 64))[tid];
    __syncthreads();
    float ar[4], az[4], an[4];
    float br = bih[d], bz = bih[64 + d], bn = bih[128 + d];
    #pragma unroll
    for (int j = 0; j < 4; j++) { ar[j] = br; az[j] = bz; an[j] = bn; }
    #pragma unroll 8
    for (int k = 0; k < 64; k++) {
        float wr = WtI_l[k * 192 + d];
        float wz = WtI_l[k * 192 + 64 + d];
        float wn = WtI_l[k * 192 + 128 + d];
        #pragma unroll
        for (int j = 0; j < 4; j++) {
            float av = at[rg + 4 * j][k];
            ar[j] = fmaf(av, wr, ar[j]);
            az[j] = fmaf(av, wz, az[j]);
            an[j] = fmaf(av, wn, an[j]);
        }
    }
    #pragma unroll
    for (int j = 0; j < 4; j++) {
        int row = row0 + rg + 4 * j;
        float ghr = gh[row * 192 + d];
        float ghz = gh[row * 192 + 64 + d];
        float ghn = gh[row * 192 + 128 + d];
        float hv  = h[row * 64 + d];
        float r = sigmoidf_(ar[j] + ghr);
        float z = sigmoidf_(az[j] + ghz);
        float n = tanhf_(an[j] + r * ghn);
        float hn = (1.f - z) * n + z * hv;
        h[row * 64 + d] = fmaxf(hn, 0.f);
    }
}

// ---------------- MLP: h = relu(h@W^T+b), in place ----------------
__global__ __launch_bounds__(256)
void mlp_layer(const float* __restrict__ WtM_m,  // [64][64]
               const float* __restrict__ b,      // [64]
               float* __restrict__ h)
{
    __shared__ float ht[16][64];
    int tid = threadIdx.x;
    int d = tid & 63, rg = tid >> 6;
    int row0 = blockIdx.x * 16;
    ((float4*)ht)[tid] = ((const float4*)(h + row0 * 64))[tid];
    __syncthreads();
    float acc[4];
    float bias = b[d];
    #pragma unroll
    for (int j = 0; j < 4; j++) acc[j] = bias;
    #pragma unroll 8
    for (int k = 0; k < 64; k++) {
        float w = WtM_m[k * 64 + d];
        #pragma unroll
        for (int j = 0; j < 4; j++) acc[j] = fmaf(ht[rg + 4 * j][k], w, acc[j]);
    }
    #pragma unroll
    for (int j = 0; j < 4; j++) {
        int row = row0 + rg + 4 * j;
        h[row * 64 + d] = fmaxf(acc[j], 0.f);
    }
}

// ---------------- final: out = h @ h^T, 64x64 tiles ----------------
__global__ __launch_bounds__(256)
void simmat(const float* __restrict__ h, float* __restrict__ out)
{
    __shared__ float Ar[64][68];   // +4 pad: 4 distinct rows/wave -> 4 distinct banks
    __shared__ float Bc[64][68];
    int tid = threadIdx.x;
    int by = blockIdx.y, bx = blockIdx.x;
    const float* hA = h + by * 64 * 64;
    const float* hB = h + bx * 64 * 64;
    #pragma unroll
    for (int i = 0; i < 4; i++) {
        int q = tid + 256 * i;
        int row = q >> 4, kq = (q & 15) << 2;
        float4 v = *((const float4*)(hA + row * 64 + kq));
        *((float4*)&Ar[row][kq]) = v;
        float4 w = *((const float4*)(hB + row * 64 + kq));
        *((float4*)&Bc[row][kq]) = w;
    }
    __syncthreads();
    int tr = tid >> 4, tc = tid & 15;
    float acc[4][4];
    #pragma unroll
    for (int i = 0; i < 4; i++)
        #pragma unroll
        for (int j = 0; j < 4; j++) acc[i][j] = 0.f;
    #pragma unroll
    for (int k0 = 0; k0 < 64; k0 += 4) {
        float4 av[4], bv[4];
        #pragma unroll
        for (int i = 0; i < 4; i++) av[i] = *((const float4*)&Ar[tr * 4 + i][k0]);
        #pragma unroll
        for (int j = 0; j < 4; j++) bv[j] = *((const float4*)&Bc[tc * 4 + j][k0]);
        #pragma unroll
        for (int i = 0; i < 4; i++)
            #pragma unroll
            for (int j = 0; j < 4; j++) {
                acc[i][j] = fmaf(av[i].x, bv[j].x, acc[i][j]);
                acc[i][j] = fmaf(av[i].y, bv[j].y, acc[i][j]);
                acc[i][j] = fmaf(av[i].z, bv[j].z, acc[i][j]);
                acc[i][j] = fmaf(av[i].w, bv[j].w, acc[i][j]);
            }
    }
    #pragma unroll
    for (int i = 0; i < 4; i++) {
        size_t row = (size_t)(by * 64 + tr * 4 + i);
        int col = bx * 64 + tc * 4;
        float4 o = make_float4(acc[i][0], acc[i][1], acc[i][2], acc[i][3]);
        *((float4*)(out + row * 8192 + col)) = o;
    }
}

extern "C" void kernel_launch(void* const* d_in, const int* in_sizes, int n_in,
                              void* d_out, int out_size, void* d_ws, size_t ws_size,
                              hipStream_t stream)
{
    const float* node_feat = (const float*)d_in[0];
    const int*   edge_src  = (const int*)d_in[1];
    const int*   edge_dst  = (const int*)d_in[2];
    const float* conv_W    = (const float*)d_in[3];
    const float* conv_b    = (const float*)d_in[4];
    const float* gru_Wih   = (const float*)d_in[5];
    const float* gru_Whh   = (const float*)d_in[6];
    const float* gru_bih   = (const float*)d_in[7];
    const float* gru_bhh   = (const float*)d_in[8];
    const float* mlp_W     = (const float*)d_in[9];
    const float* mlp_b     = (const float*)d_in[10];
    int E = in_sizes[1];
    float* out = (float*)d_out;

    // workspace carve (~15.9 MB total)
    float* ws  = (float*)d_ws;
    float* h   = ws;                          // 8192*64
    float* hl  = h  + NNODES * DDIM;          // 8192*64
    float* gh  = hl + NNODES * DDIM;          // 8192*192
    float* a   = gh + NNODES * 192;           // 8192*64
    float* WtA = a  + NNODES * DDIM;          // 9*64*256
    float* WtI = WtA + NLAYER * 64 * 256;     // 9*64*192
    float* WtM = WtI + NLAYER * 64 * 192;     // 3*64*64
    int* counts   = (int*)(WtM + NMLP * 64 * 64);  // 8192
    int* row_ptr  = counts + NNODES;               // 8193
    int* row_fill = row_ptr + NNODES + 1;          // 8192
    int* col_idx  = row_fill + NNODES;             // E

    prep_weights<<<1056, 256, 0, stream>>>(conv_W, gru_Whh, gru_Wih, mlp_W, WtA, WtI, WtM);
    init_h<<<(NNODES * DDIM + 255) / 256, 256, 0, stream>>>(node_feat, h, counts);
    count_deg<<<(E + 255) / 256, 256, 0, stream>>>(edge_dst, E, counts);
    scan_deg<<<1, 256, 0, stream>>>(counts, row_ptr, row_fill);
    scatter_edges<<<(E + 255) / 256, 256, 0, stream>>>(edge_src, edge_dst, E, row_fill, col_idx);

    for (int l = 0; l < NLAYER; l++) {
        layer_pre<<<NNODES / 16, 256, 0, stream>>>(h, WtA + l * 16384,
                                                   conv_b + l * 64, gru_bhh + l * 192, hl, gh);
        aggregate<<<NNODES / 4, 256, 0, stream>>>(hl, row_ptr, col_idx, a);
        layer_gru<<<NNODES / 16, 256, 0, stream>>>(a, WtI + l * 12288,
                                                   gru_bih + l * 192, gh, h);
    }
    for (int m = 0; m < NMLP; m++) {
        mlp_layer<<<NNODES / 16, 256, 0, stream>>>(WtM + m * 4096, mlp_b + m * 64, h);
    }
    dim3 g(128, 128);
    simmat<<<g, 256, 0, stream>>>(h, out);
}